// Round 1
// baseline (259.186 us; speedup 1.0000x reference)
//
#include <hip/hip_runtime.h>

typedef __bf16 bf16x8 __attribute__((ext_vector_type(8)));
typedef float f32x4 __attribute__((ext_vector_type(4)));

// workspace layout (bytes):
//   Kt : [125][288][32] bf16  -> 2,304,000 B at offset 0
//   xb : [2][36][36][36][32] bf16 -> 5,971,968 B at offset 2,304,000
#define KT_BYTES 2304000

__device__ __forceinline__ unsigned short f2bf(float f) {
    unsigned int u = __builtin_bit_cast(unsigned int, f);
    unsigned int r = (u + 0x7fffu + ((u >> 16) & 1u)) >> 16;
    return (unsigned short)r;
}

__device__ __forceinline__ float sus(float x) {
    return x > 0.0f ? expf(-1.0f / x) : 0.0f;
}

// ---- build conv kernel Kt[v][o][ci] (bf16), v = dx*25+dy*5+dz ----
__global__ void build_kt(const float* __restrict__ w0, const float* __restrict__ w1,
                         const float* __restrict__ w2, const float* __restrict__ wlin,
                         unsigned short* __restrict__ kt) {
    const int v = blockIdx.x;
    const int dx = v / 25, dy = (v / 5) % 5, dz = v % 5;
    const float lx = (float)(dx - 2), ly = (float)(dy - 2), lz = (float)(dz - 2);
    const float nr = sqrtf(lx * lx + ly * ly + lz * lz);

    float emb[8];
    const float tt = nr * (9.0f / 2.5f);          // n / step
    const float C = 1.14136f * expf(2.0f);
    #pragma unroll
    for (int j = 1; j <= 8; j++) {
        float d = tt - (float)j;
        emb[j - 1] = C * sus(d + 1.0f) * sus(1.0f - d);
    }

    float ux = 0.f, uy = 0.f, uz = 0.f;
    if (nr > 0.0f) { ux = lx / nr; uy = ly / nr; uz = lz / nr; }
    float Y[9];
    const float s3 = 1.7320508075688772f, s15 = 3.872983346207417f;
    Y[0] = 1.0f;
    Y[1] = s3 * uy; Y[2] = s3 * uz; Y[3] = s3 * ux;       // l=1 order: y,z,x
    Y[4] = s15 * ux * uy;
    Y[5] = s15 * uy * uz;
    Y[6] = 1.1180339887498949f * (2.0f * uz * uz - ux * ux - uy * uy); // sqrt(5)/2
    Y[7] = s15 * ux * uz;
    Y[8] = 0.5f * s15 * (ux * ux - uy * uy);

    const float rfan = 0.17677669529663687f;  // 1/sqrt(32)

    for (int e = threadIdx.x; e < 288 * 32; e += blockDim.x) {
        const int o = e >> 5, ci = e & 31;
        const float* w; int co, yi;
        if (o < 32)       { w = w0; co = o; yi = 0; }
        else if (o < 128) { int t = o - 32;  w = w1; co = t / 3; yi = 1 + t % 3; }
        else              { int t = o - 128; w = w2; co = t / 5; yi = 4 + t % 5; }
        float s = 0.0f;
        #pragma unroll
        for (int k = 0; k < 8; k++) s += emb[k] * w[k * 1024 + ci * 32 + co];
        float val = s * (1.0f / 125.0f) * Y[yi] * rfan;
        if (v == 62) val = (o < 32) ? wlin[ci * 32 + o] * rfan : 0.0f;  // center override
        kt[(v * 288 + o) * 32 + ci] = f2bf(val);
    }
}

// ---- pad + convert x to bf16: xb[n][36][36][36][32] ----
__global__ void pad_x(const float* __restrict__ x, unsigned short* __restrict__ xb) {
    int idx = blockIdx.x * blockDim.x + threadIdx.x;
    if (idx >= 2 * 36 * 36 * 36 * 32) return;
    const int ci = idx & 31;
    int t = idx >> 5;
    const int pz = t % 36; t /= 36;
    const int py = t % 36; t /= 36;
    const int px = t % 36; const int nn = t / 36;
    const int gx = px - 2, gy = py - 2, gz = pz - 2;
    float val = 0.0f;
    if ((unsigned)gx < 32u && (unsigned)gy < 32u && (unsigned)gz < 32u)
        val = x[((((size_t)nn * 32 + gx) * 32 + gy) * 32 + gz) * 32 + ci];
    xb[idx] = f2bf(val);
}

__device__ __forceinline__ bool activev(int v) {
    int dx = v / 25 - 2, dy = (v / 5) % 5 - 2, dz = v % 5 - 2;
    return dx * dx + dy * dy + dz * dz <= 6;   // nr^2 < 6.25 or center
}

// ---- conv: implicit GEMM, block = 128 positions x 288 outputs ----
// LDS: patch [5][8][36][32] bf16 = 92160 B ; Bt 2 x [288][32] bf16 = 36864 B
__global__ __launch_bounds__(512, 2) void conv_mfma(const unsigned short* __restrict__ xb,
                                                    const unsigned short* __restrict__ kt,
                                                    float* __restrict__ out) {
    __shared__ __align__(16) char lds[129024];
    const int tid = threadIdx.x;
    const int lane = tid & 63;
    const int wv = tid >> 6;
    const int l15 = lane & 15, l16 = lane >> 4;
    const int wm = wv & 3, wn = wv >> 2;
    const int o0 = wn * 144;

    const int b = blockIdx.x;
    const int nn = b >> 8;
    const int rem = b & 255;
    const int x0 = rem >> 3;        // output x of this block
    const int y0 = (rem & 7) << 2;  // output y base (4 rows)

    // stage input patch (once): padded coords x' = x0+dx, y' = y0+dyy, z' full 36
    {
        const unsigned short* xsrc = xb + (size_t)nn * 1492992;
        for (int p = tid; p < 5760; p += 512) {        // 16B units
            int r = p / 144;                           // (dx,dyy) run, 144 units each
            int off = p - r * 144;
            int dx = r >> 3, dyy = r & 7;
            uint4 val = *((const uint4*)(xsrc + (size_t)((x0 + dx) * 36 + (y0 + dyy)) * 1152) + off);
            int a = p << 4;
            a ^= ((a >> 7) & 7) << 4;                  // XOR swizzle
            *(uint4*)(lds + a) = val;
        }
    }

    auto stageB = [&](int vv, int sb) {
        const uint4* src = (const uint4*)(kt + vv * 9216);
        #pragma unroll
        for (int u0 = 0; u0 < 3; u0++) {
            int u = tid + u0 * 512;
            if (u < 1152) {
                uint4 val = src[u];
                int a = 92160 + sb * 18432 + (u << 4);
                a ^= ((a >> 7) & 7) << 4;
                *(uint4*)(lds + a) = val;
            }
        }
    };

    f32x4 acc[2][9];
    #pragma unroll
    for (int i = 0; i < 2; i++)
        #pragma unroll
        for (int j = 0; j < 9; j++)
            acc[i][j] = (f32x4){0.f, 0.f, 0.f, 0.f};

    int vcur = 0;
    while (!activev(vcur)) vcur++;
    stageB(vcur, 0);
    __syncthreads();

    int sel = 0;
    while (vcur < 125) {
        int vnext = vcur + 1;
        while (vnext < 125 && !activev(vnext)) vnext++;
        if (vnext < 125) stageB(vnext, sel ^ 1);

        const int dx = vcur / 25, dy = (vcur / 5) % 5, dz = vcur % 5;
        bf16x8 afr[2];
        #pragma unroll
        for (int s2 = 0; s2 < 2; s2++) {
            // m = wm*32 + s2*16 + l15  ->  ym = wm, zm = s2*16 + l15
            int row = (dx * 8 + wm + dy) * 36 + (s2 * 16 + l15 + dz);
            int a = (row << 6) + (l16 << 4);
            a ^= ((a >> 7) & 7) << 4;
            afr[s2] = *(const bf16x8*)(lds + a);
        }
        #pragma unroll
        for (int nt = 0; nt < 9; nt++) {
            int o = o0 + nt * 16 + l15;
            int a = 92160 + sel * 18432 + (o << 6) + (l16 << 4);
            a ^= ((a >> 7) & 7) << 4;
            bf16x8 bfr = *(const bf16x8*)(lds + a);
            acc[0][nt] = __builtin_amdgcn_mfma_f32_16x16x32_bf16(afr[0], bfr, acc[0][nt], 0, 0, 0);
            acc[1][nt] = __builtin_amdgcn_mfma_f32_16x16x32_bf16(afr[1], bfr, acc[1][nt], 0, 0, 0);
        }
        __syncthreads();
        sel ^= 1;
        vcur = vnext;
    }

    // epilogue: D row = 4*(lane>>4)+reg, col = lane&15
    #pragma unroll
    for (int s2 = 0; s2 < 2; s2++) {
        #pragma unroll
        for (int r = 0; r < 4; r++) {
            int zm = s2 * 16 + l16 * 4 + r;   // ym = wm
            size_t base = ((((size_t)nn * 32 + x0) * 32 + (y0 + wm)) * 32 + zm) * 288 + o0 + l15;
            #pragma unroll
            for (int nt = 0; nt < 9; nt++)
                out[base + nt * 16] = acc[s2][nt][r];
        }
    }
}

extern "C" void kernel_launch(void* const* d_in, const int* in_sizes, int n_in,
                              void* d_out, int out_size, void* d_ws, size_t ws_size,
                              hipStream_t stream) {
    const float* x    = (const float*)d_in[0];
    const float* w0   = (const float*)d_in[1];
    const float* w1   = (const float*)d_in[2];
    const float* w2   = (const float*)d_in[3];
    const float* wlin = (const float*)d_in[4];
    unsigned short* kt = (unsigned short*)d_ws;
    unsigned short* xb = (unsigned short*)((char*)d_ws + KT_BYTES);
    float* out = (float*)d_out;

    hipLaunchKernelGGL(build_kt, dim3(125), dim3(256), 0, stream, w0, w1, w2, wlin, kt);
    hipLaunchKernelGGL(pad_x, dim3((2 * 36 * 36 * 36 * 32) / 256), dim3(256), 0, stream, x, xb);
    hipLaunchKernelGGL(conv_mfma, dim3(512), dim3(512), 0, stream, xb, kt, out);
}

// Round 2
// 139.761 us; speedup vs baseline: 1.8545x; 1.8545x over previous
//
#include <hip/hip_runtime.h>

typedef __bf16 bf16x8 __attribute__((ext_vector_type(8)));
typedef float f32x4 __attribute__((ext_vector_type(4)));

// workspace layout (bytes):
//   Kt : [125][288][32] bf16 (pre-swizzled within each 18432-B slice) at offset 0
//   xb : [2][36][36][36][32] bf16 -> 5,971,968 B at offset 2,304,000
#define KT_BYTES 2304000

__device__ __forceinline__ unsigned short f2bf(float f) {
    unsigned int u = __builtin_bit_cast(unsigned int, f);
    unsigned int r = (u + 0x7fffu + ((u >> 16) & 1u)) >> 16;
    return (unsigned short)r;
}

__device__ __forceinline__ float sus(float x) {
    return x > 0.0f ? expf(-1.0f / x) : 0.0f;
}

// ---- build conv kernel Kt[v][o][ci] (bf16), v = dx*25+dy*5+dz ----
// Stored PRE-SWIZZLED: byte addr within slice r -> r ^ (((r>>7)&7)<<4), so that
// a linear global_load_lds copy + swizzled ds_read returns the original value.
__global__ void build_kt(const float* __restrict__ w0, const float* __restrict__ w1,
                         const float* __restrict__ w2, const float* __restrict__ wlin,
                         unsigned short* __restrict__ kt) {
    const int v = blockIdx.x;
    const int dx = v / 25, dy = (v / 5) % 5, dz = v % 5;
    const float lx = (float)(dx - 2), ly = (float)(dy - 2), lz = (float)(dz - 2);
    const float nr = sqrtf(lx * lx + ly * ly + lz * lz);

    float emb[8];
    const float tt = nr * (9.0f / 2.5f);          // n / step
    const float C = 1.14136f * expf(2.0f);
    #pragma unroll
    for (int j = 1; j <= 8; j++) {
        float d = tt - (float)j;
        emb[j - 1] = C * sus(d + 1.0f) * sus(1.0f - d);
    }

    float ux = 0.f, uy = 0.f, uz = 0.f;
    if (nr > 0.0f) { ux = lx / nr; uy = ly / nr; uz = lz / nr; }
    float Y[9];
    const float s3 = 1.7320508075688772f, s15 = 3.872983346207417f;
    Y[0] = 1.0f;
    Y[1] = s3 * uy; Y[2] = s3 * uz; Y[3] = s3 * ux;       // l=1 order: y,z,x
    Y[4] = s15 * ux * uy;
    Y[5] = s15 * uy * uz;
    Y[6] = 1.1180339887498949f * (2.0f * uz * uz - ux * ux - uy * uy); // sqrt(5)/2
    Y[7] = s15 * ux * uz;
    Y[8] = 0.5f * s15 * (ux * ux - uy * uy);

    const float rfan = 0.17677669529663687f;  // 1/sqrt(32)

    for (int e = threadIdx.x; e < 288 * 32; e += blockDim.x) {
        const int o = e >> 5, ci = e & 31;
        const float* w; int co, yi;
        if (o < 32)       { w = w0; co = o; yi = 0; }
        else if (o < 128) { int t = o - 32;  w = w1; co = t / 3; yi = 1 + t % 3; }
        else              { int t = o - 128; w = w2; co = t / 5; yi = 4 + t % 5; }
        float s = 0.0f;
        #pragma unroll
        for (int k = 0; k < 8; k++) s += emb[k] * w[k * 1024 + ci * 32 + co];
        float val = s * (1.0f / 125.0f) * Y[yi] * rfan;
        if (v == 62) val = (o < 32) ? wlin[ci * 32 + o] * rfan : 0.0f;  // center override
        int r = o * 64 + ci * 2;                    // logical byte addr in slice
        int rs = r ^ (((r >> 7) & 7) << 4);         // pre-apply swizzle (involution)
        kt[v * 9216 + (rs >> 1)] = f2bf(val);
    }
}

// ---- pad + convert x to bf16: xb[n][36][36][36][32] ----
__global__ void pad_x(const float* __restrict__ x, unsigned short* __restrict__ xb) {
    int idx = blockIdx.x * blockDim.x + threadIdx.x;
    if (idx >= 2 * 36 * 36 * 36 * 32) return;
    const int ci = idx & 31;
    int t = idx >> 5;
    const int pz = t % 36; t /= 36;
    const int py = t % 36; t /= 36;
    const int px = t % 36; const int nn = t / 36;
    const int gx = px - 2, gy = py - 2, gz = pz - 2;
    float val = 0.0f;
    if ((unsigned)gx < 32u && (unsigned)gy < 32u && (unsigned)gz < 32u)
        val = x[((((size_t)nn * 32 + gx) * 32 + gy) * 32 + gz) * 32 + ci];
    xb[idx] = f2bf(val);
}

__device__ __forceinline__ bool activev(int v) {
    int dx = v / 25 - 2, dy = (v / 5) % 5 - 2, dz = v % 5 - 2;
    return dx * dx + dy * dy + dz * dz <= 6;   // kernel is exactly 0 beyond r=2.5
}

__device__ __forceinline__ int nextv(int v) {
    v++;
    while (v < 125 && !activev(v)) v++;
    return v < 125 ? v : -1;
}

// ---- conv: implicit GEMM, block = 256 positions x 288 outputs, 8 waves ----
// LDS: patch [6][8][36][32] bf16 = 110592 B ; B dbuf 2 x [288][32] bf16 = 36864 B
#define PATCH_BYTES 110592
#define BSLOT 18432

__global__ __launch_bounds__(512, 2) void conv_mfma(const unsigned short* __restrict__ xb,
                                                    const unsigned short* __restrict__ kt,
                                                    float* __restrict__ out) {
    __shared__ __align__(16) char lds[PATCH_BYTES + 2 * BSLOT];
    const int tid = threadIdx.x;
    const int lane = tid & 63;
    const int wv = tid >> 6;
    const int l15 = lane & 15, l16 = lane >> 4;
    const int wm = wv & 3, wn = wv >> 2;
    const int o0 = wn * 144;

    const int b = blockIdx.x;
    const int nn = b >> 7;
    const int X0 = 2 * ((b >> 3) & 15);   // output x base (covers X0, X0+1)
    const int Y0 = 4 * (b & 7);           // output y base (covers Y0..Y0+3)

    // ---- stage input patch (once per block): [6 x][8 y][36 z][32 ci] ----
    {
        const unsigned short* xsrc = xb + (size_t)nn * 1492992;
        for (int u = tid; u < 6912; u += 512) {       // 16B units
            int r = u / 144, off = u - r * 144;
            int xi = r >> 3, yi = r & 7;
            uint4 val = *((const uint4*)(xsrc + (size_t)((X0 + xi) * 36 + (Y0 + yi)) * 1152) + off);
            int a = u << 4;
            a ^= ((a >> 7) & 7) << 4;                 // XOR swizzle
            *(uint4*)(lds + a) = val;
        }
    }

    // ---- B staging: 18432 B/voxel, 2304 B per wave, 3 global_load_lds each ----
    auto stageB = [&](int vv, int sb) {
        const char* src = (const char*)(kt + vv * 9216) + wv * 2304;
        char* dst = lds + PATCH_BYTES + sb * BSLOT + wv * 2304;
        __builtin_amdgcn_global_load_lds(
            (const __attribute__((address_space(1))) void*)(src + lane * 16),
            (__attribute__((address_space(3))) void*)dst, 16, 0, 0);
        __builtin_amdgcn_global_load_lds(
            (const __attribute__((address_space(1))) void*)(src + 1024 + lane * 16),
            (__attribute__((address_space(3))) void*)(dst + 1024), 16, 0, 0);
        __builtin_amdgcn_global_load_lds(
            (const __attribute__((address_space(1))) void*)(src + 2048 + lane * 4),
            (__attribute__((address_space(3))) void*)(dst + 2048), 4, 0, 0);
    };

    f32x4 acc[4][9];
    #pragma unroll
    for (int i = 0; i < 4; i++)
        #pragma unroll
        for (int j = 0; j < 9; j++)
            acc[i][j] = (f32x4){0.f, 0.f, 0.f, 0.f};

    int vcur = nextv(-1);
    int vnext = nextv(vcur);
    stageB(vcur, 0);
    __syncthreads();   // patch + first B slice ready (drains all vmcnt)

    int sel = 0;
    while (vcur >= 0) {
        if (vnext >= 0) stageB(vnext, sel ^ 1);   // issue DMA EARLY (hidden under compute)

        const int dx = vcur / 25, dyy = (vcur / 5) % 5, dzz = vcur % 5;
        // A fragments: wave covers m = wm*64 + s*16 + row; xo = wm>>1, 2 y-rows, 2 z-halves
        bf16x8 afr[4];
        #pragma unroll
        for (int s = 0; s < 4; s++) {
            int xi = (wm >> 1) + dx;
            int yi = (wm & 1) * 2 + (s >> 1) + dyy;
            int zi = (s & 1) * 16 + l15 + dzz;
            int a = ((xi * 8 + yi) * 36 + zi) * 64 + (l16 << 4);
            a ^= ((a >> 7) & 7) << 4;
            afr[s] = *(const bf16x8*)(lds + a);
        }
        #pragma unroll
        for (int nt = 0; nt < 9; nt++) {
            int o = o0 + nt * 16 + l15;
            int a = PATCH_BYTES + sel * BSLOT + (o << 6) + (l16 << 4);
            a ^= ((a >> 7) & 7) << 4;
            bf16x8 bfr = *(const bf16x8*)(lds + a);
            #pragma unroll
            for (int s = 0; s < 4; s++)
                acc[s][nt] = __builtin_amdgcn_mfma_f32_16x16x32_bf16(afr[s], bfr, acc[s][nt], 0, 0, 0);
        }

        if (vnext >= 0) __syncthreads();   // drains the 3 DMAs (issued ~500 cyc ago)
        sel ^= 1;
        vcur = vnext;
        vnext = (vnext >= 0) ? nextv(vnext) : -1;
    }

    // ---- epilogue: D row = 4*l16 + r (m), col = l15 (n) ----
    #pragma unroll
    for (int s = 0; s < 4; s++) {
        const int x = X0 + (wm >> 1);
        const int y = Y0 + (wm & 1) * 2 + (s >> 1);
        #pragma unroll
        for (int r = 0; r < 4; r++) {
            int z = (s & 1) * 16 + l16 * 4 + r;
            size_t base = ((((size_t)nn * 32 + x) * 32 + y) * 32 + z) * 288 + o0 + l15;
            #pragma unroll
            for (int nt = 0; nt < 9; nt++)
                out[base + nt * 16] = acc[s][nt][r];
        }
    }
}

extern "C" void kernel_launch(void* const* d_in, const int* in_sizes, int n_in,
                              void* d_out, int out_size, void* d_ws, size_t ws_size,
                              hipStream_t stream) {
    const float* x    = (const float*)d_in[0];
    const float* w0   = (const float*)d_in[1];
    const float* w1   = (const float*)d_in[2];
    const float* w2   = (const float*)d_in[3];
    const float* wlin = (const float*)d_in[4];
    unsigned short* kt = (unsigned short*)d_ws;
    unsigned short* xb = (unsigned short*)((char*)d_ws + KT_BYTES);
    float* out = (float*)d_out;

    hipLaunchKernelGGL(build_kt, dim3(125), dim3(256), 0, stream, w0, w1, w2, wlin, kt);
    hipLaunchKernelGGL(pad_x, dim3((2 * 36 * 36 * 36 * 32) / 256), dim3(256), 0, stream, x, xb);
    hipLaunchKernelGGL(conv_mfma, dim3(256), dim3(512), 0, stream, xb, kt, out);
}

// Round 3
// 129.283 us; speedup vs baseline: 2.0048x; 1.0810x over previous
//
#include <hip/hip_runtime.h>

typedef __bf16 bf16x8 __attribute__((ext_vector_type(8)));
typedef float f32x4 __attribute__((ext_vector_type(4)));

// workspace layout (bytes):
//   Kt : [125][288][32] bf16 (pre-swizzled within each 18432-B slice) at offset 0
//   xb : [2][36][36][36][32] bf16 -> 5,971,968 B at offset 2,304,000
#define KT_BYTES 2304000
#define NS 18432   // one B slice (288*32*2 B)

__device__ __forceinline__ unsigned short f2bf(float f) {
    unsigned int u = __builtin_bit_cast(unsigned int, f);
    unsigned int r = (u + 0x7fffu + ((u >> 16) & 1u)) >> 16;
    return (unsigned short)r;
}

__device__ __forceinline__ float sus(float x) {
    return x > 0.0f ? expf(-1.0f / x) : 0.0f;
}

// ---- active-voxel table (81 voxels with r^2 <= 6), compile-time ----
struct VoxTab { int kt[81]; int xb[81]; };
constexpr VoxTab mk_tab() {
    VoxTab t{};
    int n = 0;
    for (int dx = 0; dx < 5; dx++)
        for (int dy = 0; dy < 5; dy++)
            for (int dz = 0; dz < 5; dz++) {
                int a = dx - 2, b = dy - 2, c = dz - 2;
                if (a * a + b * b + c * c <= 6) {
                    t.kt[n] = (dx * 25 + dy * 5 + dz) * NS;            // byte offset into Kt
                    t.xb[n] = ((dx * 36 + dy) * 36 + dz) * 32;         // short offset into xb
                    n++;
                }
            }
    return t;
}
__constant__ VoxTab TAB = mk_tab();

// ---- build conv kernel Kt[v][o][ci] (bf16, pre-swizzled) ----
// w0/w1/w2 staged in LDS (96 KB) so the 8-term k-sum reads LDS, not scattered global.
__global__ __launch_bounds__(512) void build_kt(const float* __restrict__ w0,
                                                const float* __restrict__ w1,
                                                const float* __restrict__ w2,
                                                const float* __restrict__ wlin,
                                                unsigned short* __restrict__ kt) {
    __shared__ float lw[24576];   // [3][8][32][32] floats = 96 KB
    const int tid = threadIdx.x;
    {
        const float4* s0 = (const float4*)w0;
        const float4* s1 = (const float4*)w1;
        const float4* s2 = (const float4*)w2;
        for (int u = tid; u < 6144; u += 512) {
            int wsel = u >> 11, r = u & 2047;
            float4 v = (wsel == 0 ? s0[r] : (wsel == 1 ? s1[r] : s2[r]));
            ((float4*)lw)[u] = v;
        }
    }
    __syncthreads();

    const int v = blockIdx.x;
    const int dx = v / 25, dy = (v / 5) % 5, dz = v % 5;
    const float lx = (float)(dx - 2), ly = (float)(dy - 2), lz = (float)(dz - 2);
    const float nr = sqrtf(lx * lx + ly * ly + lz * lz);

    float emb[8];
    const float tt = nr * (9.0f / 2.5f);
    const float C = 1.14136f * expf(2.0f);
    #pragma unroll
    for (int j = 1; j <= 8; j++) {
        float d = tt - (float)j;
        emb[j - 1] = C * sus(d + 1.0f) * sus(1.0f - d);
    }

    float ux = 0.f, uy = 0.f, uz = 0.f;
    if (nr > 0.0f) { ux = lx / nr; uy = ly / nr; uz = lz / nr; }
    float Y[9];
    const float s3 = 1.7320508075688772f, s15 = 3.872983346207417f;
    Y[0] = 1.0f;
    Y[1] = s3 * uy; Y[2] = s3 * uz; Y[3] = s3 * ux;
    Y[4] = s15 * ux * uy;
    Y[5] = s15 * uy * uz;
    Y[6] = 1.1180339887498949f * (2.0f * uz * uz - ux * ux - uy * uy);
    Y[7] = s15 * ux * uz;
    Y[8] = 0.5f * s15 * (ux * ux - uy * uy);

    const float rfan = 0.17677669529663687f;  // 1/sqrt(32)

    for (int e = tid; e < 9216; e += 512) {
        const int ci = e / 288, o = e % 288;       // o fast -> light LDS conflicts
        int wsel, co, yi;
        if (o < 32)       { wsel = 0; co = o; yi = 0; }
        else if (o < 128) { int t = o - 32;  wsel = 1; co = t / 3; yi = 1 + t % 3; }
        else              { int t = o - 128; wsel = 2; co = t / 5; yi = 4 + t % 5; }
        const float* w = lw + wsel * 8192;
        float s = 0.0f;
        #pragma unroll
        for (int k = 0; k < 8; k++) s += emb[k] * w[k * 1024 + ci * 32 + co];
        float val = s * (1.0f / 125.0f) * Y[yi] * rfan;
        if (v == 62) val = (o < 32) ? wlin[ci * 32 + o] * rfan : 0.0f;   // center override
        int r = o * 64 + ci * 2;                   // logical byte addr in slice
        int rs = r ^ (((r >> 7) & 7) << 4);        // pre-apply LDS swizzle (involution)
        kt[v * 9216 + (rs >> 1)] = f2bf(val);
    }
}

// ---- pad + convert x to bf16 (16B stores): xb[n][36][36][36][32] ----
__global__ void pad_x2(const float* __restrict__ x, unsigned short* __restrict__ xb) {
    int u = blockIdx.x * blockDim.x + threadIdx.x;   // one 16B unit (8 bf16)
    if (u >= 373248) return;
    const int ci8 = u & 3;
    int t = u >> 2;
    const int pz = t % 36; t /= 36;
    const int py = t % 36; t /= 36;
    const int px = t % 36; const int nn = t / 36;
    const int gx = px - 2, gy = py - 2, gz = pz - 2;
    uint4 ov = {0u, 0u, 0u, 0u};
    if ((unsigned)gx < 32u && (unsigned)gy < 32u && (unsigned)gz < 32u) {
        const float* src = x + ((((size_t)nn * 32 + gx) * 32 + gy) * 32 + gz) * 32 + ci8 * 8;
        float4 f0 = ((const float4*)src)[0];
        float4 f1 = ((const float4*)src)[1];
        ov.x = (unsigned)f2bf(f0.x) | ((unsigned)f2bf(f0.y) << 16);
        ov.y = (unsigned)f2bf(f0.z) | ((unsigned)f2bf(f0.w) << 16);
        ov.z = (unsigned)f2bf(f1.x) | ((unsigned)f2bf(f1.y) << 16);
        ov.w = (unsigned)f2bf(f1.z) | ((unsigned)f2bf(f1.w) << 16);
    }
    ((uint4*)xb)[u] = ov;
}

// ---- conv: implicit GEMM, block = 256 positions x 288 outputs, 8 waves ----
// A fragments straight from global (L2), B in a 3-slot LDS ring (55 KB),
// raw s_barrier + counted vmcnt -> no full pipeline drain.
__global__ __launch_bounds__(512, 2) void conv_mfma(const unsigned short* __restrict__ xb,
                                                    const unsigned short* __restrict__ kt,
                                                    float* __restrict__ out) {
    __shared__ __align__(16) char lds[3 * NS];
    const int tid = threadIdx.x;
    const int lane = tid & 63;
    const int wv = tid >> 6;
    const int l15 = lane & 15, l16 = lane >> 4;
    const int wm = wv & 3, wn = wv >> 2;
    const int o0 = wn * 144;

    // XCD-bijective swizzle: 256 blocks = 8 XCDs x 32 -> each XCD works one x-slab
    const int b = blockIdx.x;
    const int sw = (b & 7) * 32 + (b >> 3);
    const int nn = sw >> 7;
    const int X0 = 2 * ((sw >> 3) & 15);
    const int Y0 = 4 * (sw & 7);

    const unsigned short* xbase = xb + (size_t)nn * 1492992;

    // per-lane A global offsets (shorts), frag s: (y-off s>>1, z-half s&1)
    int aoff[4];
    #pragma unroll
    for (int s = 0; s < 4; s++) {
        int xw = X0 + (wm >> 1);
        int yw = Y0 + (wm & 1) * 2 + (s >> 1);
        int zb = (s & 1) * 16 + l15;
        aoff[s] = ((xw * 36 + yw) * 36 + zb) * 32 + l16 * 8;
    }
    // per-lane B LDS offsets (bytes, swizzled), frag nt
    int boff[9];
    #pragma unroll
    for (int nt = 0; nt < 9; nt++) {
        int a = (o0 + nt * 16 + l15) * 64 + l16 * 16;
        boff[nt] = a ^ (((a >> 7) & 7) << 4);
    }

    auto stageB = [&](int ktByte, int slot) {
        const char* src = (const char*)kt + ktByte + wv * 2304;
        char* dst = lds + slot * NS + wv * 2304;
        __builtin_amdgcn_global_load_lds(
            (const __attribute__((address_space(1))) void*)(src + lane * 16),
            (__attribute__((address_space(3))) void*)dst, 16, 0, 0);
        __builtin_amdgcn_global_load_lds(
            (const __attribute__((address_space(1))) void*)(src + 1024 + lane * 16),
            (__attribute__((address_space(3))) void*)(dst + 1024), 16, 0, 0);
        __builtin_amdgcn_global_load_lds(
            (const __attribute__((address_space(1))) void*)(src + 2048 + lane * 4),
            (__attribute__((address_space(3))) void*)(dst + 2048), 4, 0, 0);
    };

    bf16x8 Ac[4], An[4];
    f32x4 acc[4][9];
    #pragma unroll
    for (int i = 0; i < 4; i++)
        #pragma unroll
        for (int j = 0; j < 9; j++)
            acc[i][j] = (f32x4){0.f, 0.f, 0.f, 0.f};

    auto loadA = [&](bf16x8* A, int xoff) {
        #pragma unroll
        for (int s = 0; s < 4; s++)
            A[s] = *(const bf16x8*)(xbase + aoff[s] + xoff);
    };

    auto issue = [&](int ktN, int slot2, int xbN) {
        if (ktN >= 0) stageB(ktN, slot2);
        if (xbN >= 0) loadA(An, xbN);
    };

    auto compute = [&](int slot) {
        #pragma unroll
        for (int nt = 0; nt < 9; nt++) {
            bf16x8 bfr = *(const bf16x8*)(lds + slot * NS + boff[nt]);
            #pragma unroll
            for (int s = 0; s < 4; s++)
                acc[s][nt] = __builtin_amdgcn_mfma_f32_16x16x32_bf16(Ac[s], bfr, acc[s][nt], 0, 0, 0);
        }
        __builtin_amdgcn_sched_barrier(0);
        __builtin_amdgcn_s_barrier();
        #pragma unroll
        for (int s = 0; s < 4; s++) Ac[s] = An[s];
    };

    // prologue: B(0)->slot0, A(0), B(1)->slot1
    stageB(TAB.kt[0], 0);
    loadA(Ac, TAB.xb[0]);
    stageB(TAB.kt[1], 1);
    asm volatile("s_waitcnt vmcnt(3)" ::: "memory");
    __builtin_amdgcn_sched_barrier(0);
    __builtin_amdgcn_s_barrier();

    // main loop: k = 0..77 (26 groups of 3); iter k: stage B(k+2), load A(k+1), compute k
    #pragma unroll 1
    for (int g = 0; g < 26; g++) {
        const int k = g * 3;
        issue(TAB.kt[k + 2], 2, TAB.xb[k + 1]);
        asm volatile("s_waitcnt vmcnt(7)" ::: "memory");
        compute(0);
        issue(TAB.kt[k + 3], 0, TAB.xb[k + 2]);
        asm volatile("s_waitcnt vmcnt(7)" ::: "memory");
        compute(1);
        issue(TAB.kt[k + 4], 1, TAB.xb[k + 3]);
        asm volatile("s_waitcnt vmcnt(7)" ::: "memory");
        compute(2);
    }
    // tail: k = 78, 79, 80
    issue(TAB.kt[80], 2, TAB.xb[79]);
    asm volatile("s_waitcnt vmcnt(7)" ::: "memory");
    compute(0);
    issue(-1, 0, TAB.xb[80]);
    asm volatile("s_waitcnt vmcnt(4)" ::: "memory");
    compute(1);
    issue(-1, 0, -1);
    asm volatile("s_waitcnt vmcnt(0)" ::: "memory");
    compute(2);

    // ---- epilogue: D row = 4*l16 + r (m), col = l15 (n) ----
    #pragma unroll
    for (int s = 0; s < 4; s++) {
        const int x = X0 + (wm >> 1);
        const int y = Y0 + (wm & 1) * 2 + (s >> 1);
        #pragma unroll
        for (int r = 0; r < 4; r++) {
            int z = (s & 1) * 16 + l16 * 4 + r;
            size_t base = ((((size_t)nn * 32 + x) * 32 + y) * 32 + z) * 288 + o0 + l15;
            #pragma unroll
            for (int nt = 0; nt < 9; nt++)
                out[base + nt * 16] = acc[s][nt][r];
        }
    }
}

extern "C" void kernel_launch(void* const* d_in, const int* in_sizes, int n_in,
                              void* d_out, int out_size, void* d_ws, size_t ws_size,
                              hipStream_t stream) {
    const float* x    = (const float*)d_in[0];
    const float* w0   = (const float*)d_in[1];
    const float* w1   = (const float*)d_in[2];
    const float* w2   = (const float*)d_in[3];
    const float* wlin = (const float*)d_in[4];
    unsigned short* kt = (unsigned short*)d_ws;
    unsigned short* xb = (unsigned short*)((char*)d_ws + KT_BYTES);
    float* out = (float*)d_out;

    hipLaunchKernelGGL(build_kt, dim3(125), dim3(512), 0, stream, w0, w1, w2, wlin, kt);
    hipLaunchKernelGGL(pad_x2, dim3(1458), dim3(256), 0, stream, x, xb);
    hipLaunchKernelGGL(conv_mfma, dim3(256), dim3(512), 0, stream, xb, kt, out);
}